// Round 9
// baseline (298.125 us; speedup 1.0000x reference)
//
#include <hip/hip_runtime.h>
#include <hip/hip_bf16.h>

typedef __hip_bfloat16 bf16;
typedef __attribute__((ext_vector_type(8))) short short8;   // 8 bf16 = 4 VGPR
typedef __attribute__((ext_vector_type(4))) float f32x4;

#define HWP 3136
#define WD 56
#define PW 58          // padded width (1-px zero border)
#define PADP 3364      // 58*58
#define CC 128
#define MIDM 32
#define OGN 512
#define NB 4

// workspace offsets in FLOAT units (all multiples of 4 -> 16B aligned)
enum : int {
  OFF_FLAG = 0,                          // [4]
  OFF_W2F  = 4,                          // fp32 [o][m] 512x32
  OFF_SC2  = OFF_W2F + OGN*MIDM,         // [32]  bn2 scale
  OFF_SH2  = OFF_SC2 + MIDM,             // [32]  bas0 = sc2*b1 + (bn2 shift)
  OFF_B2F  = OFF_SH2 + MIDM,             // [512]
  OFF_GNG  = OFF_B2F + OGN,              // [512]
  OFF_GNB  = OFF_GNG + OGN,              // [512]
  OFF_GPART= OFF_GNB + OGN,              // fp32 [b][128][1056] Gram+S1 partials
  OFF_PQ   = OFF_GPART + NB*128*1056,    // float2 [b][512]
  OFF_SS1  = OFF_PQ + NB*OGN*2,          // float2 [128]
  OFF_SSV  = OFF_SS1 + CC*2,             // float2 [512]
  OFF_WKB  = OFF_SSV + OGN*2,            // bf16 [d][c] 128x128
  OFF_WVB  = OFF_WKB + CC*CC/2,          // bf16 [o][c] 512x128
  OFF_W1AB = OFF_WVB + OGN*CC/2,         // bf16 [m][c] 32x128
  OFF_W1BB = OFF_W1AB + MIDM*CC/2,       // bf16 [m][c] 32x128
  OFF_HQT  = OFF_W1BB + MIDM*CC/2,       // bf16 [b][pix][m]  hq' = sc2*hq+bas0
  OFF_GKT  = OFF_HQT + NB*HWP*MIDM/2,    // bf16 [b][pp58][m] gk' = sc2*gk, PADDED
  OFF_VT   = OFF_GKT + NB*PADP*MIDM/2,   // bf16 [b][pp58][o] PADDED, zero border
  OFF_XT   = OFF_VT + NB*PADP*OGN/2,     // bf16 [b][pix][c]
  WS_TOTAL = OFF_XT + NB*HWP*CC/2        // ~21 MB
};

__device__ __forceinline__ float b2f(unsigned short u) {
  bf16 h; *(unsigned short*)&h = u; return __bfloat162float(h);
}
__device__ __forceinline__ unsigned short f2b(float f) {
  bf16 h = __float2bfloat16(f); return *(unsigned short*)&h;
}
__device__ __forceinline__ float ldmix(const void* p, size_t i, bool isbf) {
  return isbf ? __bfloat162float(((const bf16*)p)[i]) : ((const float*)p)[i];
}
__device__ __forceinline__ f32x4 mfma16(short8 a, short8 b, f32x4 c) {
  return __builtin_amdgcn_mfma_f32_16x16x32_bf16(a, b, c, 0, 0, 0);
}
__device__ __forceinline__ bool detect_bf(const unsigned short* xr) {
  int cnt = 0;
#pragma unroll
  for (int i = 0; i < 32; i++) {
    short8 v = *(const short8*)(xr + i*8);
#pragma unroll
    for (int j = 0; j < 8; j++) {
      int e = (((unsigned short)v[j]) >> 7) & 0xFF;
      cnt += (e >= 141) ? 1 : 0;
    }
  }
  return cnt < 8;
}

// ---- L1: detect + params + x->xt transpose (blocks 0..391) + border zero ----
__global__ __launch_bounds__(256) void k_prep(
    const void* __restrict__ x,  const void* __restrict__ Wk,
    const void* __restrict__ bn1_g, const void* __restrict__ bn1_b,
    const void* __restrict__ bn1_m, const void* __restrict__ bn1_v,
    const void* __restrict__ W1, const void* __restrict__ b1,
    const void* __restrict__ bn2_g, const void* __restrict__ bn2_b,
    const void* __restrict__ bn2_m, const void* __restrict__ bn2_v,
    const void* __restrict__ W2, const void* __restrict__ b2,
    const void* __restrict__ gn_g, const void* __restrict__ gn_b,
    const void* __restrict__ Wv,
    const void* __restrict__ bnv_g, const void* __restrict__ bnv_b,
    const void* __restrict__ bnv_m, const void* __restrict__ bnv_v,
    float* __restrict__ ws) {
  __shared__ unsigned short tile[32*130];
  const bool isbf = detect_bf((const unsigned short*)x);
  int blk = blockIdx.x, tid = threadIdx.x;
  if (blk == 0 && tid == 0) ws[OFF_FLAG] = isbf ? 1.f : 0.f;
  int gid = blk*256 + tid, gstride = gridDim.x*256;
  unsigned short* wkb = (unsigned short*)(ws + OFF_WKB);
  unsigned short* wvb = (unsigned short*)(ws + OFF_WVB);
  unsigned short* w1ab = (unsigned short*)(ws + OFF_W1AB);
  unsigned short* w1bb = (unsigned short*)(ws + OFF_W1BB);
  float2* ss1 = (float2*)(ws + OFF_SS1);
  float2* ssv = (float2*)(ws + OFF_SSV);
  for (int i = gid; i < CC*CC; i += gstride) wkb[i] = f2b(ldmix(Wk, i, isbf));
  for (int i = gid; i < OGN*CC; i += gstride) wvb[i] = f2b(ldmix(Wv, i, isbf));
  for (int i = gid; i < MIDM*CC; i += gstride) {
    int m = i / CC, c = i % CC;
    w1ab[i] = f2b(ldmix(W1, (size_t)m*(2*CC) + c, isbf));
    w1bb[i] = f2b(ldmix(W1, (size_t)m*(2*CC) + CC + c, isbf));
  }
  for (int i = gid; i < OGN*MIDM; i += gstride) ws[OFF_W2F + i] = ldmix(W2, i, isbf);
  for (int i = gid; i < CC; i += gstride) {
    float s = ldmix(bn1_g, i, isbf) / sqrtf(ldmix(bn1_v, i, isbf) + 1e-5f);
    ss1[i] = make_float2(s, ldmix(bn1_b, i, isbf) - ldmix(bn1_m, i, isbf) * s);
  }
  for (int i = gid; i < MIDM; i += gstride) {
    float s = ldmix(bn2_g, i, isbf) / sqrtf(ldmix(bn2_v, i, isbf) + 1e-5f);
    ws[OFF_SC2 + i] = s;
    // bas0 = sc2*b1 + (bn2_b - bn2_m*sc2)
    ws[OFF_SH2 + i] = s*ldmix(b1, i, isbf)
                    + ldmix(bn2_b, i, isbf) - ldmix(bn2_m, i, isbf)*s;
  }
  for (int i = gid; i < OGN; i += gstride) {
    float s = ldmix(bnv_g, i, isbf) / sqrtf(ldmix(bnv_v, i, isbf) + 1e-5f);
    ssv[i] = make_float2(s, ldmix(bnv_b, i, isbf) - ldmix(bnv_m, i, isbf) * s);
    ws[OFF_B2F + i] = ldmix(b2, i, isbf);
    ws[OFF_GNG + i] = ldmix(gn_g, i, isbf);
    ws[OFF_GNB + i] = ldmix(gn_b, i, isbf);
  }
  if (blk < 392) {
    int b = blk / 98, pix0 = (blk % 98)*32;
#pragma unroll
    for (int k = 0; k < 16; k++) {
      int idx = tid + k*256;
      int c = idx >> 5, pl = idx & 31;
      tile[pl*130 + c] = f2b(ldmix(x, ((size_t)b*CC + c)*HWP + pix0 + pl, isbf));
    }
    __syncthreads();
    unsigned short* xt = (unsigned short*)(ws + OFF_XT);
#pragma unroll
    for (int k = 0; k < 16; k++) {
      int idx = tid + k*256;
      int c = idx & 127, pl = idx >> 7;
      xt[((size_t)b*HWP + pix0 + pl)*CC + c] = tile[pl*130 + c];
    }
  } else {
    // zero: vt border (912 pps x 64 o-chunks) + whole gkt_pad
    const int NV = 912*64, NG = NB*PADP*4;
    const short8 z = {0,0,0,0,0,0,0,0};
    unsigned short* vt = (unsigned short*)(ws + OFF_VT);
    unsigned short* gk = (unsigned short*)(ws + OFF_GKT);
    for (int u = (blk-392)*256 + tid; u < NV + NG; u += 28*256) {
      if (u < NV) {
        int bpp = u >> 6, och = u & 63;
        int b = bpp / 228, j = bpp - b*228;
        int pp;
        if (j < 58)       pp = j;
        else if (j < 116) pp = 57*PW + (j - 58);
        else if (j < 172) pp = (j - 116 + 1)*PW;
        else              pp = (j - 172 + 1)*PW + 57;
        *(short8*)(vt + ((size_t)b*PADP + pp)*OGN + och*8) = z;
      } else {
        int u2 = u - NV;
        int b = u2 / (PADP*4), rem = u2 - b*(PADP*4);
        int pp = rem >> 2, mch = rem & 3;
        *(short8*)(gk + ((size_t)b*PADP + pp)*MIDM + mch*8) = z;
      }
    }
  }
}

// ---- L2: keq (blocks 0..195) | v (blocks 196..979) ----
__global__ __launch_bounds__(256, 4) void k_mid(float* __restrict__ ws) {
  __shared__ unsigned short keL[4][16][136];
  int bid = blockIdx.x, tid = threadIdx.x;
  int w = tid >> 6, lane = tid & 63, q = lane >> 4, l16 = lane & 15;
  if (bid < 196) {
    int b = bid / 49, bx = bid - (bid/49)*49;
    int pix = bx*64 + w*16 + l16;
    const unsigned short* xt = (const unsigned short*)(ws + OFF_XT) + ((size_t)b*HWP + pix)*CC;
    short8 Bx[4];
#pragma unroll
    for (int kk = 0; kk < 4; kk++) Bx[kk] = *(const short8*)(xt + kk*32 + q*8);
    const unsigned short* wkb = (const unsigned short*)(ws + OFF_WKB);
    const float2* ss = (const float2*)(ws + OFF_SS1);
#pragma unroll
    for (int ot = 0; ot < 8; ot++) {
      int drow = ot*16 + l16;
      f32x4 c = {0.f, 0.f, 0.f, 0.f};
#pragma unroll
      for (int kk = 0; kk < 4; kk++)
        c = mfma16(*(const short8*)(wkb + (size_t)drow*CC + kk*32 + q*8), Bx[kk], c);
      int d0 = ot*16 + q*4;
      ushort4 st;
      { float2 s = ss[d0+0]; st.x = f2b(fmaxf(s.x*c[0] + s.y, 0.f)); }
      { float2 s = ss[d0+1]; st.y = f2b(fmaxf(s.x*c[1] + s.y, 0.f)); }
      { float2 s = ss[d0+2]; st.z = f2b(fmaxf(s.x*c[2] + s.y, 0.f)); }
      { float2 s = ss[d0+3]; st.w = f2b(fmaxf(s.x*c[3] + s.y, 0.f)); }
      *(ushort4*)&keL[w][l16][d0] = st;
    }
    __syncthreads();
    short8 Bk[4];
#pragma unroll
    for (int kk = 0; kk < 4; kk++) Bk[kk] = *(const short8*)&keL[w][l16][kk*32 + q*8];
    const unsigned short* w1a = (const unsigned short*)(ws + OFF_W1AB);
    const unsigned short* w1b = (const unsigned short*)(ws + OFF_W1BB);
    int h0 = pix / WD, w0 = pix - h0*WD;
    int pp = (h0+1)*PW + (w0+1);
    unsigned short* hqt = (unsigned short*)(ws + OFF_HQT) + ((size_t)b*HWP + pix)*MIDM;
    unsigned short* gkt = (unsigned short*)(ws + OFF_GKT) + ((size_t)b*PADP + pp)*MIDM;
#pragma unroll
    for (int mt = 0; mt < 2; mt++) {
      int mrow = mt*16 + l16;
      f32x4 ch = {0.f,0.f,0.f,0.f}, cg = {0.f,0.f,0.f,0.f};
#pragma unroll
      for (int kk = 0; kk < 4; kk++) {
        ch = mfma16(*(const short8*)(w1a + (size_t)mrow*CC + kk*32 + q*8), Bx[kk], ch);
        cg = mfma16(*(const short8*)(w1b + (size_t)mrow*CC + kk*32 + q*8), Bk[kk], cg);
      }
      int m0 = mt*16 + q*4;
      ushort4 sh, sg;
      // hq' = sc2*hq + bas0 ; gk' = sc2*gk
      sh.x = f2b(ws[OFF_SC2+m0+0]*ch[0] + ws[OFF_SH2+m0+0]);
      sh.y = f2b(ws[OFF_SC2+m0+1]*ch[1] + ws[OFF_SH2+m0+1]);
      sh.z = f2b(ws[OFF_SC2+m0+2]*ch[2] + ws[OFF_SH2+m0+2]);
      sh.w = f2b(ws[OFF_SC2+m0+3]*ch[3] + ws[OFF_SH2+m0+3]);
      sg.x = f2b(ws[OFF_SC2+m0+0]*cg[0]);
      sg.y = f2b(ws[OFF_SC2+m0+1]*cg[1]);
      sg.z = f2b(ws[OFF_SC2+m0+2]*cg[2]);
      sg.w = f2b(ws[OFF_SC2+m0+3]*cg[3]);
      *(ushort4*)(hqt + m0) = sh;
      *(ushort4*)(gkt + m0) = sg;
    }
  } else {
    int vid = bid - 196;
    int bx = vid % 49, rest = vid / 49;
    int by = rest & 3, b = rest >> 2;
    int pix = bx*64 + w*16 + l16;
    int h0 = pix / WD, w0 = pix - h0*WD;
    int pp = (h0+1)*PW + (w0+1);
    const unsigned short* xt = (const unsigned short*)(ws + OFF_XT) + ((size_t)b*HWP + pix)*CC;
    short8 B[4];
#pragma unroll
    for (int kk = 0; kk < 4; kk++) B[kk] = *(const short8*)(xt + kk*32 + q*8);
    const unsigned short* wvb = (const unsigned short*)(ws + OFF_WVB);
    const float2* ss = (const float2*)(ws + OFF_SSV);
    unsigned short* vt = (unsigned short*)(ws + OFF_VT) + ((size_t)b*PADP + pp)*OGN;
#pragma unroll
    for (int ot = 0; ot < 8; ot++) {
      int orow = by*128 + ot*16 + l16;
      f32x4 c = {0.f, 0.f, 0.f, 0.f};
#pragma unroll
      for (int kk = 0; kk < 4; kk++)
        c = mfma16(*(const short8*)(wvb + (size_t)orow*CC + kk*32 + q*8), B[kk], c);
      int o0 = by*128 + ot*16 + q*4;
      ushort4 st;
      { float2 s = ss[o0+0]; st.x = f2b(s.x*c[0] + s.y); }
      { float2 s = ss[o0+1]; st.y = f2b(s.x*c[1] + s.y); }
      { float2 s = ss[o0+2]; st.z = f2b(s.x*c[2] + s.y); }
      { float2 s = ss[o0+3]; st.w = f2b(s.x*c[3] + s.y); }
      *(ushort4*)(vt + o0) = st;
    }
  }
}

// ---- L3: h = relu(hq'+gk') on the fly -> Gram/S1 partials. grid (32,4) ----
__global__ __launch_bounds__(256) void k_gramh(float* __restrict__ ws) {
  __shared__ unsigned short tileT[32][264];
  int b = blockIdx.y, bk = blockIdx.x;
  int tid = threadIdx.x;
  int w = tid >> 6, lane = tid & 63, q = lane >> 4, l16 = lane & 15;
  const int base = bk * 882;                 // 28224 / 32
  const unsigned short* hqt = (const unsigned short*)(ws + OFF_HQT) + (size_t)b*HWP*MIDM;
  const unsigned short* gkp = (const unsigned short*)(ws + OFF_GKT) + (size_t)b*PADP*MIDM;
  f32x4 gLL={0,0,0,0}, gLH={0,0,0,0}, gHH={0,0,0,0}, sL={0,0,0,0}, sH={0,0,0,0};
  short8 ones;
#pragma unroll
  for (int j = 0; j < 8; j++) ones[j] = (short)0x3F80;
  for (int t = 0; t < 4; t++) {
    int r = t*256 + tid;
    bool valid = r < 882;
    int R = valid ? (base + r) : 0;
    int p = R / HWP, pix = R - p*HWP;
    int h0 = pix / WD, w0 = pix - h0*WD;
    int npp = (h0 + p/3)*PW + (w0 + p - (p/3)*3);
    const unsigned short* hq = hqt + (size_t)pix*MIDM;
    const unsigned short* gk = gkp + (size_t)npp*MIDM;
#pragma unroll
    for (int ch = 0; ch < 4; ch++) {
      short8 th = *(const short8*)(hq + ch*8);
      short8 tg = *(const short8*)(gk + ch*8);
#pragma unroll
      for (int j = 0; j < 8; j++) {
        float v = fmaxf(b2f((unsigned short)th[j]) + b2f((unsigned short)tg[j]), 0.f);
        tileT[ch*8 + j][tid] = valid ? f2b(v) : (unsigned short)0;
      }
    }
    __syncthreads();
#pragma unroll
    for (int cc = 0; cc < 2; cc++) {
      int c = w*2 + cc;
      short8 alo = *(const short8*)&tileT[l16][c*32 + q*8];
      short8 ahi = *(const short8*)&tileT[l16+16][c*32 + q*8];
      gLL = mfma16(alo, alo, gLL);
      gLH = mfma16(alo, ahi, gLH);
      gHH = mfma16(ahi, ahi, gHH);
      sL = mfma16(alo, ones, sL);
      sH = mfma16(ahi, ones, sH);
    }
    __syncthreads();
  }
  float* blob = ws + OFF_GPART + ((size_t)((b*32 + bk)*4 + w))*1056;
#pragma unroll
  for (int r = 0; r < 4; r++) {
    int row = q*4 + r;
    blob[row*32 + l16]             = gLL[r];
    blob[row*32 + 16 + l16]        = gLH[r];
    blob[(16 + l16)*32 + row]      = gLH[r];   // HL = LH^T
    blob[(16 + row)*32 + 16 + l16] = gHH[r];
  }
  if (l16 == 0) {
#pragma unroll
    for (int r = 0; r < 4; r++) {
      blob[1024 + q*4 + r]      = sL[r];
      blob[1024 + 16 + q*4 + r] = sH[r];
    }
  }
}

// ---- L4: GN stats -> PQ. grid (4) x 512 ----
__global__ __launch_bounds__(512) void k_stats(float* __restrict__ ws) {
  __shared__ float Gs[MIDM*MIDM], S1s[MIDM], saS[OGN], sqS[OGN], muS[128], invS[128];
  int b = blockIdx.x, o = threadIdx.x;
  for (int e = o; e < 1056; e += 512) {
    float s = 0.f;
    const float* pb = ws + OFF_GPART + (size_t)b*128*1056 + e;
    for (int p = 0; p < 128; p++) s += pb[(size_t)p*1056];
    if (e < 1024) Gs[e] = s; else S1s[e - 1024] = s;
  }
  __syncthreads();
  float w2[MIDM];
#pragma unroll
  for (int m = 0; m < MIDM; m++) w2[m] = ws[OFF_W2F + o*MIDM + m];
  float dotS = 0.f;
#pragma unroll
  for (int m = 0; m < MIDM; m++) dotS += w2[m] * S1s[m];
  float quad = 0.f;
  for (int a = 0; a < MIDM; a++) {
    float t = 0.f;
#pragma unroll
    for (int c = 0; c < MIDM; c++) t += Gs[a*MIDM + c] * w2[c];
    quad += w2[a] * t;
  }
  float b2o = ws[OFF_B2F + o];
  const float M = 9.f * HWP;
  saS[o] = dotS + b2o * M;
  sqS[o] = quad + 2.f*b2o*dotS + b2o*b2o*M;
  __syncthreads();
  if (o < 128) {
    float sa = saS[4*o] + saS[4*o+1] + saS[4*o+2] + saS[4*o+3];
    float sq = sqS[4*o] + sqS[4*o+1] + sqS[4*o+2] + sqS[4*o+3];
    const float invN = 1.f / (4.f * M);
    float mu = sa * invN;
    float var = sq * invN - mu*mu;
    muS[o] = mu;
    invS[o] = 1.f / sqrtf(var + 1e-5f);
  }
  __syncthreads();
  int co = o >> 2;
  float alpha = ws[OFF_GNG + o] * invS[co];
  ((float2*)(ws + OFF_PQ))[b*OGN + o] =
      make_float2(alpha, alpha*b2o + ws[OFF_GNB + o] - muS[co]*alpha);
}

// ---- L5: epilogue, 8x8 px tiles, h recomputed from LDS gk' + reg hq'.
//      out = sum_p sum_o ((P.W2).h + Q) * v_pad.  grid (49,4,4), 256 thr ----
#define VST 136   // vt tile row stride (u16)
#define GST 40    // gk tile row stride (u16)
__global__ __launch_bounds__(256, 4) void k_out(const float* __restrict__ ws,
                                                void* __restrict__ outp) {
  __shared__ unsigned short tileV[100*VST];   // 27.2 KB
  __shared__ unsigned short tileG[100*GST];   // 8 KB
  int b = blockIdx.z, by = blockIdx.y;
  int t = blockIdx.x;                  // 0..48 -> 7x7 tiles of 8x8 px
  int th = t / 7, tw = t - (t/7)*7;
  int tid = threadIdx.x;
  int w = tid >> 6, lane = tid & 63, q = lane >> 4, l16 = lane & 15;
  int wbase = (th*8)*PW + (tw*8);      // padded pp of window (0,0); max 3363 in-range
  // stage vt window: 100 pps x 128 o
  const unsigned short* vsrc = (const unsigned short*)(ws + OFF_VT)
      + (size_t)b*PADP*OGN + (size_t)by*128;
#pragma unroll
  for (int i = 0; i < 7; i++) {
    int u = i*256 + tid;
    if (u < 1600) {
      int wp = u >> 4, col = (u & 15)*8;
      int pp = wbase + (wp/10)*PW + (wp - (wp/10)*10);
      *(short8*)&tileV[wp*VST + col] = *(const short8*)(vsrc + (size_t)pp*OGN + col);
    }
  }
  // stage gk' window: 100 pps x 32 m
  const unsigned short* gsrc = (const unsigned short*)(ws + OFF_GKT) + (size_t)b*PADP*MIDM;
#pragma unroll
  for (int i = 0; i < 2; i++) {
    int u = i*256 + tid;
    if (u < 400) {
      int wp = u >> 2, col = (u & 3)*8;
      int pp = wbase + (wp/10)*PW + (wp - (wp/10)*10);
      *(short8*)&tileG[wp*GST + col] = *(const short8*)(gsrc + (size_t)pp*MIDM + col);
    }
  }
  // lane's pixel: wave w owns tile rows 2w, 2w+1
  int lr = 2*w + (l16 >> 3), lc = l16 & 7;
  int pix = (th*8 + lr)*WD + (tw*8 + lc);
  int lbase = (lr + 1)*10 + (lc + 1);     // local window coord of center tap
  const bool isbf = ws[OFF_FLAG] > 0.5f;
  const float2* pq = (const float2*)(ws + OFF_PQ) + b*OGN;
  short8 A[8];
  f32x4 Qv[8];
#pragma unroll
  for (int ot = 0; ot < 8; ot++) {
    int orow = by*128 + ot*16 + l16;
    float P = pq[orow].x;
    const float* wrow = ws + OFF_W2F + (size_t)orow*MIDM + q*8;
    short8 a;
#pragma unroll
    for (int j = 0; j < 8; j++) a[j] = (short)f2b(P * wrow[j]);
    A[ot] = a;
    int o0 = by*128 + ot*16 + q*4;
    f32x4 qv = { pq[o0+0].y, pq[o0+1].y, pq[o0+2].y, pq[o0+3].y };
    Qv[ot] = qv;
  }
  // hq' fragment (lane-local, 16 B) -> floats
  const unsigned short* hq = (const unsigned short*)(ws + OFF_HQT)
      + ((size_t)b*HWP + pix)*MIDM + q*8;
  short8 hqv = *(const short8*)hq;
  float hqf[8];
#pragma unroll
  for (int j = 0; j < 8; j++) hqf[j] = b2f((unsigned short)hqv[j]);
  float acc[8];
#pragma unroll
  for (int ot = 0; ot < 8; ot++) acc[ot] = 0.f;
  __syncthreads();
  const int doff2[9] = {-11, -10, -9, -1, 0, 1, 9, 10, 11};
#pragma unroll
  for (int p = 0; p < 9; p++) {
    int lw = lbase + doff2[p];
    // recompute h fragment: relu(hq' + gk')
    short8 gv = *(const short8*)&tileG[lw*GST + q*8];
    short8 B;
#pragma unroll
    for (int j = 0; j < 8; j++)
      B[j] = (short)f2b(fmaxf(hqf[j] + b2f((unsigned short)gv[j]), 0.f));
    const unsigned short* vrow = &tileV[lw*VST];
#pragma unroll
    for (int ot = 0; ot < 8; ot++) {
      f32x4 c = {0.f, 0.f, 0.f, 0.f};
      c = mfma16(A[ot], B, c);
      ushort4 vv = *(const ushort4*)(vrow + ot*16 + q*4);
      acc[ot] += (c[0] + Qv[ot][0])*b2f(vv.x) + (c[1] + Qv[ot][1])*b2f(vv.y)
               + (c[2] + Qv[ot][2])*b2f(vv.z) + (c[3] + Qv[ot][3])*b2f(vv.w);
    }
  }
#pragma unroll
  for (int ot = 0; ot < 8; ot++) {
    int co = by*32 + ot*4 + q;
    size_t oidx = ((size_t)b*128 + co)*HWP + pix;
    if (isbf) ((unsigned short*)outp)[oidx] = f2b(acc[ot]);
    else      ((float*)outp)[oidx] = acc[ot];
  }
}

extern "C" void kernel_launch(void* const* d_in, const int* in_sizes, int n_in,
                              void* d_out, int out_size, void* d_ws, size_t ws_size,
                              hipStream_t stream) {
  float* ws = (float*)d_ws;
  hipLaunchKernelGGL(k_prep, dim3(420), dim3(256), 0, stream,
                     d_in[0], d_in[1], d_in[2], d_in[3], d_in[4], d_in[5],
                     d_in[6], d_in[7], d_in[8], d_in[9], d_in[10], d_in[11],
                     d_in[12], d_in[13], d_in[14], d_in[15], d_in[16],
                     d_in[17], d_in[18], d_in[19], d_in[20], ws);
  hipLaunchKernelGGL(k_mid,  dim3(980),      dim3(256), 0, stream, ws);
  hipLaunchKernelGGL(k_gramh,dim3(32, 4),    dim3(256), 0, stream, ws);
  hipLaunchKernelGGL(k_stats,dim3(4),        dim3(512), 0, stream, ws);
  hipLaunchKernelGGL(k_out,  dim3(49, 4, 4), dim3(256), 0, stream, ws, d_out);
}

// Round 11
// 229.511 us; speedup vs baseline: 1.2990x; 1.2990x over previous
//
#include <hip/hip_runtime.h>
#include <hip/hip_bf16.h>

typedef __hip_bfloat16 bf16;
typedef __attribute__((ext_vector_type(8))) short short8;   // 8 bf16 = 4 VGPR
typedef __attribute__((ext_vector_type(4))) float f32x4;

#define HWP 3136
#define WD 56
#define PW 58          // padded width (1-px zero border)
#define PADP 3364      // 58*58
#define CC 128
#define MIDM 32
#define OGN 512
#define NB 4

// workspace offsets in FLOAT units (all multiples of 4 -> 16B aligned)
enum : int {
  OFF_FLAG = 0,                          // [4]
  OFF_W2F  = 4,                          // fp32 [o][m] 512x32
  OFF_SC2  = OFF_W2F + OGN*MIDM,         // [32]
  OFF_SH2  = OFF_SC2 + MIDM,             // [32]
  OFF_B1F  = OFF_SH2 + MIDM,             // [32]
  OFF_B2F  = OFF_B1F + MIDM,             // [512]
  OFF_GNG  = OFF_B2F + OGN,              // [512]
  OFF_GNB  = OFF_GNG + OGN,              // [512]
  OFF_GPART= OFF_GNB + OGN,              // fp32 [b][128][1056] Gram+S1 partials
  OFF_PQ   = OFF_GPART + NB*128*1056,    // float2 [b][512]
  OFF_SS1  = OFF_PQ + NB*OGN*2,          // float2 [128]
  OFF_SSV  = OFF_SS1 + CC*2,             // float2 [512]
  OFF_WKB  = OFF_SSV + OGN*2,            // bf16 [d][c] 128x128
  OFF_WVB  = OFF_WKB + CC*CC/2,          // bf16 [o][c] 512x128
  OFF_W1AB = OFF_WVB + OGN*CC/2,         // bf16 [m][c] 32x128
  OFF_W1BB = OFF_W1AB + MIDM*CC/2,       // bf16 [m][c] 32x128
  OFF_HQT  = OFF_W1BB + MIDM*CC/2,       // bf16 [b][pix][m] (unpadded)
  OFF_GKT  = OFF_HQT + NB*HWP*MIDM/2,    // bf16 [b][pp58][m] PADDED, zero border
  OFF_VT   = OFF_GKT + NB*PADP*MIDM/2,   // bf16 [b][pp58][o] PADDED, zero border
  OFF_R1   = OFF_VT + NB*PADP*OGN/2,     // union region
  OFF_XT   = OFF_R1,                     // bf16 [b][pix][c]    (phase 1)
  OFF_HS   = OFF_R1,                     // bf16 [b][p][pix][m] (phase 2)
  WS_TOTAL = OFF_R1 + NB*9*HWP*MIDM/2    // ~25 MB
};

__device__ __forceinline__ float b2f(unsigned short u) {
  bf16 h; *(unsigned short*)&h = u; return __bfloat162float(h);
}
__device__ __forceinline__ unsigned short f2b(float f) {
  bf16 h = __float2bfloat16(f); return *(unsigned short*)&h;
}
__device__ __forceinline__ float ldmix(const void* p, size_t i, bool isbf) {
  return isbf ? __bfloat162float(((const bf16*)p)[i]) : ((const float*)p)[i];
}
__device__ __forceinline__ f32x4 mfma16(short8 a, short8 b, f32x4 c) {
  return __builtin_amdgcn_mfma_f32_16x16x32_bf16(a, b, c, 0, 0, 0);
}
__device__ __forceinline__ bool detect_bf(const unsigned short* xr) {
  int cnt = 0;
#pragma unroll
  for (int i = 0; i < 32; i++) {
    short8 v = *(const short8*)(xr + i*8);
#pragma unroll
    for (int j = 0; j < 8; j++) {
      int e = (((unsigned short)v[j]) >> 7) & 0xFF;
      cnt += (e >= 141) ? 1 : 0;
    }
  }
  return cnt < 8;
}

// ---- L1: detect + params + x->xt transpose (blocks 0..391) + border zero ----
__global__ __launch_bounds__(256) void k_prep(
    const void* __restrict__ x,  const void* __restrict__ Wk,
    const void* __restrict__ bn1_g, const void* __restrict__ bn1_b,
    const void* __restrict__ bn1_m, const void* __restrict__ bn1_v,
    const void* __restrict__ W1, const void* __restrict__ b1,
    const void* __restrict__ bn2_g, const void* __restrict__ bn2_b,
    const void* __restrict__ bn2_m, const void* __restrict__ bn2_v,
    const void* __restrict__ W2, const void* __restrict__ b2,
    const void* __restrict__ gn_g, const void* __restrict__ gn_b,
    const void* __restrict__ Wv,
    const void* __restrict__ bnv_g, const void* __restrict__ bnv_b,
    const void* __restrict__ bnv_m, const void* __restrict__ bnv_v,
    float* __restrict__ ws) {
  __shared__ unsigned short tile[32*130];
  const bool isbf = detect_bf((const unsigned short*)x);
  int blk = blockIdx.x, tid = threadIdx.x;
  if (blk == 0 && tid == 0) ws[OFF_FLAG] = isbf ? 1.f : 0.f;
  int gid = blk*256 + tid, gstride = gridDim.x*256;
  unsigned short* wkb = (unsigned short*)(ws + OFF_WKB);
  unsigned short* wvb = (unsigned short*)(ws + OFF_WVB);
  unsigned short* w1ab = (unsigned short*)(ws + OFF_W1AB);
  unsigned short* w1bb = (unsigned short*)(ws + OFF_W1BB);
  float2* ss1 = (float2*)(ws + OFF_SS1);
  float2* ssv = (float2*)(ws + OFF_SSV);
  for (int i = gid; i < CC*CC; i += gstride) wkb[i] = f2b(ldmix(Wk, i, isbf));
  for (int i = gid; i < OGN*CC; i += gstride) wvb[i] = f2b(ldmix(Wv, i, isbf));
  for (int i = gid; i < MIDM*CC; i += gstride) {
    int m = i / CC, c = i % CC;
    w1ab[i] = f2b(ldmix(W1, (size_t)m*(2*CC) + c, isbf));
    w1bb[i] = f2b(ldmix(W1, (size_t)m*(2*CC) + CC + c, isbf));
  }
  for (int i = gid; i < OGN*MIDM; i += gstride) ws[OFF_W2F + i] = ldmix(W2, i, isbf);
  for (int i = gid; i < CC; i += gstride) {
    float s = ldmix(bn1_g, i, isbf) / sqrtf(ldmix(bn1_v, i, isbf) + 1e-5f);
    ss1[i] = make_float2(s, ldmix(bn1_b, i, isbf) - ldmix(bn1_m, i, isbf) * s);
  }
  for (int i = gid; i < MIDM; i += gstride) {
    float s = ldmix(bn2_g, i, isbf) / sqrtf(ldmix(bn2_v, i, isbf) + 1e-5f);
    ws[OFF_SC2 + i] = s;
    ws[OFF_SH2 + i] = ldmix(bn2_b, i, isbf) - ldmix(bn2_m, i, isbf)*s;
    ws[OFF_B1F + i] = ldmix(b1, i, isbf);
  }
  for (int i = gid; i < OGN; i += gstride) {
    float s = ldmix(bnv_g, i, isbf) / sqrtf(ldmix(bnv_v, i, isbf) + 1e-5f);
    ssv[i] = make_float2(s, ldmix(bnv_b, i, isbf) - ldmix(bnv_m, i, isbf) * s);
    ws[OFF_B2F + i] = ldmix(b2, i, isbf);
    ws[OFF_GNG + i] = ldmix(gn_g, i, isbf);
    ws[OFF_GNB + i] = ldmix(gn_b, i, isbf);
  }
  if (blk < 392) {
    int b = blk / 98, pix0 = (blk % 98)*32;
#pragma unroll
    for (int k = 0; k < 16; k++) {
      int idx = tid + k*256;
      int c = idx >> 5, pl = idx & 31;
      tile[pl*130 + c] = f2b(ldmix(x, ((size_t)b*CC + c)*HWP + pix0 + pl, isbf));
    }
    __syncthreads();
    unsigned short* xt = (unsigned short*)(ws + OFF_XT);
#pragma unroll
    for (int k = 0; k < 16; k++) {
      int idx = tid + k*256;
      int c = idx & 127, pl = idx >> 7;
      xt[((size_t)b*HWP + pix0 + pl)*CC + c] = tile[pl*130 + c];
    }
  } else {
    // zero: vt border (912 pps x 64 o-chunks) + whole gkt_pad
    const int NV = 912*64, NG = NB*PADP*4;
    const short8 z = {0,0,0,0,0,0,0,0};
    unsigned short* vt = (unsigned short*)(ws + OFF_VT);
    unsigned short* gk = (unsigned short*)(ws + OFF_GKT);
    for (int u = (blk-392)*256 + tid; u < NV + NG; u += 28*256) {
      if (u < NV) {
        int bpp = u >> 6, och = u & 63;
        int b = bpp / 228, j = bpp - b*228;
        int pp;
        if (j < 58)       pp = j;
        else if (j < 116) pp = 57*PW + (j - 58);
        else if (j < 172) pp = (j - 116 + 1)*PW;
        else              pp = (j - 172 + 1)*PW + 57;
        *(short8*)(vt + ((size_t)b*PADP + pp)*OGN + och*8) = z;
      } else {
        int u2 = u - NV;
        int b = u2 / (PADP*4), rem = u2 - b*(PADP*4);
        int pp = rem >> 2, mch = rem & 3;
        *(short8*)(gk + ((size_t)b*PADP + pp)*MIDM + mch*8) = z;
      }
    }
  }
}

// ---- L2: keq (blocks 0..195) | v (blocks 196..979) ----
__global__ __launch_bounds__(256, 4) void k_mid(float* __restrict__ ws) {
  __shared__ unsigned short keL[4][16][136];
  int bid = blockIdx.x, tid = threadIdx.x;
  int w = tid >> 6, lane = tid & 63, q = lane >> 4, l16 = lane & 15;
  if (bid < 196) {
    int b = bid / 49, bx = bid - (bid/49)*49;
    int pix = bx*64 + w*16 + l16;
    const unsigned short* xt = (const unsigned short*)(ws + OFF_XT) + ((size_t)b*HWP + pix)*CC;
    short8 Bx[4];
#pragma unroll
    for (int kk = 0; kk < 4; kk++) Bx[kk] = *(const short8*)(xt + kk*32 + q*8);
    const unsigned short* wkb = (const unsigned short*)(ws + OFF_WKB);
    const float2* ss = (const float2*)(ws + OFF_SS1);
#pragma unroll
    for (int ot = 0; ot < 8; ot++) {
      int drow = ot*16 + l16;
      f32x4 c = {0.f, 0.f, 0.f, 0.f};
#pragma unroll
      for (int kk = 0; kk < 4; kk++)
        c = mfma16(*(const short8*)(wkb + (size_t)drow*CC + kk*32 + q*8), Bx[kk], c);
      int d0 = ot*16 + q*4;
      ushort4 st;
      { float2 s = ss[d0+0]; st.x = f2b(fmaxf(s.x*c[0] + s.y, 0.f)); }
      { float2 s = ss[d0+1]; st.y = f2b(fmaxf(s.x*c[1] + s.y, 0.f)); }
      { float2 s = ss[d0+2]; st.z = f2b(fmaxf(s.x*c[2] + s.y, 0.f)); }
      { float2 s = ss[d0+3]; st.w = f2b(fmaxf(s.x*c[3] + s.y, 0.f)); }
      *(ushort4*)&keL[w][l16][d0] = st;
    }
    __syncthreads();
    short8 Bk[4];
#pragma unroll
    for (int kk = 0; kk < 4; kk++) Bk[kk] = *(const short8*)&keL[w][l16][kk*32 + q*8];
    const unsigned short* w1a = (const unsigned short*)(ws + OFF_W1AB);
    const unsigned short* w1b = (const unsigned short*)(ws + OFF_W1BB);
    int h0 = pix / WD, w0 = pix - h0*WD;
    int pp = (h0+1)*PW + (w0+1);
    unsigned short* hqt = (unsigned short*)(ws + OFF_HQT) + ((size_t)b*HWP + pix)*MIDM;
    unsigned short* gkt = (unsigned short*)(ws + OFF_GKT) + ((size_t)b*PADP + pp)*MIDM;
#pragma unroll
    for (int mt = 0; mt < 2; mt++) {
      int mrow = mt*16 + l16;
      f32x4 ch = {0.f,0.f,0.f,0.f}, cg = {0.f,0.f,0.f,0.f};
#pragma unroll
      for (int kk = 0; kk < 4; kk++) {
        ch = mfma16(*(const short8*)(w1a + (size_t)mrow*CC + kk*32 + q*8), Bx[kk], ch);
        cg = mfma16(*(const short8*)(w1b + (size_t)mrow*CC + kk*32 + q*8), Bk[kk], cg);
      }
      int m0 = mt*16 + q*4;
      ushort4 sh, sg;
      sh.x = f2b(ch[0]); sh.y = f2b(ch[1]); sh.z = f2b(ch[2]); sh.w = f2b(ch[3]);
      sg.x = f2b(cg[0]); sg.y = f2b(cg[1]); sg.z = f2b(cg[2]); sg.w = f2b(cg[3]);
      *(ushort4*)(hqt + m0) = sh;
      *(ushort4*)(gkt + m0) = sg;
    }
  } else {
    int vid = bid - 196;
    int bx = vid % 49, rest = vid / 49;
    int by = rest & 3, b = rest >> 2;
    int pix = bx*64 + w*16 + l16;
    int h0 = pix / WD, w0 = pix - h0*WD;
    int pp = (h0+1)*PW + (w0+1);
    const unsigned short* xt = (const unsigned short*)(ws + OFF_XT) + ((size_t)b*HWP + pix)*CC;
    short8 B[4];
#pragma unroll
    for (int kk = 0; kk < 4; kk++) B[kk] = *(const short8*)(xt + kk*32 + q*8);
    const unsigned short* wvb = (const unsigned short*)(ws + OFF_WVB);
    const float2* ss = (const float2*)(ws + OFF_SSV);
    unsigned short* vt = (unsigned short*)(ws + OFF_VT) + ((size_t)b*PADP + pp)*OGN;
#pragma unroll
    for (int ot = 0; ot < 8; ot++) {
      int orow = by*128 + ot*16 + l16;
      f32x4 c = {0.f, 0.f, 0.f, 0.f};
#pragma unroll
      for (int kk = 0; kk < 4; kk++)
        c = mfma16(*(const short8*)(wvb + (size_t)orow*CC + kk*32 + q*8), B[kk], c);
      int o0 = by*128 + ot*16 + q*4;
      ushort4 st;
      { float2 s = ss[o0+0]; st.x = f2b(s.x*c[0] + s.y); }
      { float2 s = ss[o0+1]; st.y = f2b(s.x*c[1] + s.y); }
      { float2 s = ss[o0+2]; st.z = f2b(s.x*c[2] + s.y); }
      { float2 s = ss[o0+3]; st.w = f2b(s.x*c[3] + s.y); }
      *(ushort4*)(vt + o0) = st;
    }
  }
}

// ---- L3: h recompute + hs write + Gram/S1 partials. grid (32,4) ----
__global__ __launch_bounds__(256) void k_gramh(float* __restrict__ ws) {
  __shared__ unsigned short tileT[32][264];
  int b = blockIdx.y, bk = blockIdx.x;
  int tid = threadIdx.x;
  int w = tid >> 6, lane = tid & 63, q = lane >> 4, l16 = lane & 15;
  const int base = bk * 882;                 // 28224 / 32
  const unsigned short* hqt = (const unsigned short*)(ws + OFF_HQT) + (size_t)b*HWP*MIDM;
  const unsigned short* gkp = (const unsigned short*)(ws + OFF_GKT) + (size_t)b*PADP*MIDM;
  unsigned short* hsb = (unsigned short*)(ws + OFF_HS) + (size_t)b*9*HWP*MIDM;
  float sc2[MIDM], bas0[MIDM];
#pragma unroll
  for (int m = 0; m < MIDM; m++) {
    sc2[m] = ws[OFF_SC2 + m];
    bas0[m] = sc2[m]*ws[OFF_B1F + m] + ws[OFF_SH2 + m];
  }
  f32x4 gLL={0,0,0,0}, gLH={0,0,0,0}, gHH={0,0,0,0}, sL={0,0,0,0}, sH={0,0,0,0};
  short8 ones;
#pragma unroll
  for (int j = 0; j < 8; j++) ones[j] = (short)0x3F80;
  for (int t = 0; t < 4; t++) {
    int r = t*256 + tid;
    bool valid = r < 882;
    int R = valid ? (base + r) : 0;
    int p = R / HWP, pix = R - p*HWP;
    int h0 = pix / WD, w0 = pix - h0*WD;
    int npp = (h0 + p/3)*PW + (w0 + p - (p/3)*3);
    const unsigned short* hq = hqt + (size_t)pix*MIDM;
    const unsigned short* gk = gkp + (size_t)npp*MIDM;
#pragma unroll
    for (int ch = 0; ch < 4; ch++) {
      short8 th = *(const short8*)(hq + ch*8);
      short8 tg = *(const short8*)(gk + ch*8);
      short8 o;
#pragma unroll
      for (int j = 0; j < 8; j++) {
        int m = ch*8 + j;
        float hv = b2f((unsigned short)th[j]) + b2f((unsigned short)tg[j]);
        float v = fmaxf(sc2[m]*hv + bas0[m], 0.f);
        o[j] = valid ? (short)f2b(v) : (short)0;
      }
      if (valid) *(short8*)(hsb + (size_t)R*MIDM + ch*8) = o;
#pragma unroll
      for (int j = 0; j < 8; j++) tileT[ch*8 + j][tid] = (unsigned short)o[j];
    }
    __syncthreads();
#pragma unroll
    for (int cc = 0; cc < 2; cc++) {
      int c = w*2 + cc;
      short8 alo = *(const short8*)&tileT[l16][c*32 + q*8];
      short8 ahi = *(const short8*)&tileT[l16+16][c*32 + q*8];
      gLL = mfma16(alo, alo, gLL);
      gLH = mfma16(alo, ahi, gLH);
      gHH = mfma16(ahi, ahi, gHH);
      sL = mfma16(alo, ones, sL);
      sH = mfma16(ahi, ones, sH);
    }
    __syncthreads();
  }
  float* blob = ws + OFF_GPART + ((size_t)((b*32 + bk)*4 + w))*1056;
#pragma unroll
  for (int r = 0; r < 4; r++) {
    int row = q*4 + r;
    blob[row*32 + l16]             = gLL[r];
    blob[row*32 + 16 + l16]        = gLH[r];
    blob[(16 + l16)*32 + row]      = gLH[r];   // HL = LH^T
    blob[(16 + row)*32 + 16 + l16] = gHH[r];
  }
  if (l16 == 0) {
#pragma unroll
    for (int r = 0; r < 4; r++) {
      blob[1024 + q*4 + r]      = sL[r];
      blob[1024 + 16 + q*4 + r] = sH[r];
    }
  }
}

// ---- L4: GN stats -> PQ. grid (4) x 512 ----
__global__ __launch_bounds__(512) void k_stats(float* __restrict__ ws) {
  __shared__ float Gs[MIDM*MIDM], S1s[MIDM], saS[OGN], sqS[OGN], muS[128], invS[128];
  int b = blockIdx.x, o = threadIdx.x;
  for (int e = o; e < 1056; e += 512) {
    float s = 0.f;
    const float* pb = ws + OFF_GPART + (size_t)b*128*1056 + e;
    for (int p = 0; p < 128; p++) s += pb[(size_t)p*1056];
    if (e < 1024) Gs[e] = s; else S1s[e - 1024] = s;
  }
  __syncthreads();
  float w2[MIDM];
#pragma unroll
  for (int m = 0; m < MIDM; m++) w2[m] = ws[OFF_W2F + o*MIDM + m];
  float dotS = 0.f;
#pragma unroll
  for (int m = 0; m < MIDM; m++) dotS += w2[m] * S1s[m];
  float quad = 0.f;
  for (int a = 0; a < MIDM; a++) {
    float t = 0.f;
#pragma unroll
    for (int c = 0; c < MIDM; c++) t += Gs[a*MIDM + c] * w2[c];
    quad += w2[a] * t;
  }
  float b2o = ws[OFF_B2F + o];
  const float M = 9.f * HWP;
  saS[o] = dotS + b2o * M;
  sqS[o] = quad + 2.f*b2o*dotS + b2o*b2o*M;
  __syncthreads();
  if (o < 128) {
    float sa = saS[4*o] + saS[4*o+1] + saS[4*o+2] + saS[4*o+3];
    float sq = sqS[4*o] + sqS[4*o+1] + sqS[4*o+2] + sqS[4*o+3];
    const float invN = 1.f / (4.f * M);
    float mu = sa * invN;
    float var = sq * invN - mu*mu;
    muS[o] = mu;
    invS[o] = 1.f / sqrtf(var + 1e-5f);
  }
  __syncthreads();
  int co = o >> 2;
  float alpha = ws[OFF_GNG + o] * invS[co];
  ((float2*)(ws + OFF_PQ))[b*OGN + o] =
      make_float2(alpha, alpha*b2o + ws[OFF_GNB + o] - muS[co]*alpha);
}

// ---- L5: epilogue. 64-px strip x 64-o tile; B-frags preloaded; VST2=68.
//      grid (49,8,4), 256 thr, 5 blocks/CU ----
#define VST2 68   // u16 row stride: 136 B (8B-aligned); 8-B LDS ops only
__global__ __launch_bounds__(256, 5) void k_out(const float* __restrict__ ws,
                                                void* __restrict__ outp) {
  __shared__ unsigned short tileV[192*VST2];   // 26.1 KB
  int b = blockIdx.z, by = blockIdx.y;         // by in [0,8): 64-o tile
  int tid = threadIdx.x;
  int w = tid >> 6, lane = tid & 63, q = lane >> 4, l16 = lane & 15;
  int pix0 = blockIdx.x*64;
  int h00 = pix0 / WD, w00 = pix0 - h00*WD;
  int wstart = (h00+1)*PW + (w00+1) - (PW+1);
  int pix = pix0 + w*16 + l16;
  // preload 9 B-fragments (hs) BEFORE the staging barrier
  const unsigned short* hsb = (const unsigned short*)(ws + OFF_HS) + (size_t)b*9*HWP*MIDM;
  short8 Bf[9];
#pragma unroll
  for (int p = 0; p < 9; p++)
    Bf[p] = *(const short8*)(hsb + ((size_t)p*HWP + pix)*MIDM + q*8);
  // stage vt window: 192 pps x 64 o, as 3072 ushort4 (8 B) chunks
  const unsigned short* vsrc = (const unsigned short*)(ws + OFF_VT)
      + (size_t)b*PADP*OGN + (size_t)by*64;
#pragma unroll
  for (int i = 0; i < 12; i++) {
    int u = i*256 + tid;                  // 0..3071
    int wp = u >> 4, col = (u & 15)*4;    // 192 rows x 16 chunks x 4 u16
    *(ushort4*)&tileV[wp*VST2 + col] =
        *(const ushort4*)(vsrc + (size_t)(wstart + wp)*OGN + col);
  }
  const bool isbf = ws[OFF_FLAG] > 0.5f;
  const float2* pq = (const float2*)(ws + OFF_PQ) + b*OGN;
  short8 A[4];
  f32x4 Qv[4];
#pragma unroll
  for (int ot = 0; ot < 4; ot++) {
    int orow = by*64 + ot*16 + l16;
    float P = pq[orow].x;
    const float* wrow = ws + OFF_W2F + (size_t)orow*MIDM + q*8;
    short8 a;
#pragma unroll
    for (int j = 0; j < 8; j++) a[j] = (short)f2b(P * wrow[j]);
    A[ot] = a;
    int o0 = by*64 + ot*16 + q*4;
    f32x4 qv = { pq[o0+0].y, pq[o0+1].y, pq[o0+2].y, pq[o0+3].y };
    Qv[ot] = qv;
  }
  int h0 = pix / WD, w0 = pix - h0*WD;
  int ppl = (h0+1)*PW + (w0+1) - wstart;
  float acc[4];
#pragma unroll
  for (int ot = 0; ot < 4; ot++) acc[ot] = 0.f;
  __syncthreads();
  const int doff[9] = {-PW-1, -PW, -PW+1, -1, 0, 1, PW-1, PW, PW+1};
#pragma unroll
  for (int p = 0; p < 9; p++) {
    int lp = ppl + doff[p];
    const unsigned short* vrow = &tileV[lp*VST2];
#pragma unroll
    for (int ot = 0; ot < 4; ot++) {
      f32x4 c = {0.f, 0.f, 0.f, 0.f};
      c = mfma16(A[ot], Bf[p], c);
      ushort4 vv = *(const ushort4*)(vrow + ot*16 + q*4);
      acc[ot] += (c[0] + Qv[ot][0])*b2f(vv.x) + (c[1] + Qv[ot][1])*b2f(vv.y)
               + (c[2] + Qv[ot][2])*b2f(vv.z) + (c[3] + Qv[ot][3])*b2f(vv.w);
    }
  }
#pragma unroll
  for (int ot = 0; ot < 4; ot++) {
    int co = by*16 + ot*4 + q;
    size_t oidx = ((size_t)b*128 + co)*HWP + pix;
    if (isbf) __builtin_nontemporal_store(f2b(acc[ot]), (unsigned short*)outp + oidx);
    else      __builtin_nontemporal_store(acc[ot], (float*)outp + oidx);
  }
}

extern "C" void kernel_launch(void* const* d_in, const int* in_sizes, int n_in,
                              void* d_out, int out_size, void* d_ws, size_t ws_size,
                              hipStream_t stream) {
  float* ws = (float*)d_ws;
  hipLaunchKernelGGL(k_prep, dim3(420), dim3(256), 0, stream,
                     d_in[0], d_in[1], d_in[2], d_in[3], d_in[4], d_in[5],
                     d_in[6], d_in[7], d_in[8], d_in[9], d_in[10], d_in[11],
                     d_in[12], d_in[13], d_in[14], d_in[15], d_in[16],
                     d_in[17], d_in[18], d_in[19], d_in[20], ws);
  hipLaunchKernelGGL(k_mid,  dim3(980),      dim3(256), 0, stream, ws);
  hipLaunchKernelGGL(k_gramh,dim3(32, 4),    dim3(256), 0, stream, ws);
  hipLaunchKernelGGL(k_stats,dim3(4),        dim3(512), 0, stream, ws);
  hipLaunchKernelGGL(k_out,  dim3(49, 8, 4), dim3(256), 0, stream, ws, d_out);
}